// Round 5
// baseline (141.969 us; speedup 1.0000x reference)
//
#include <hip/hip_runtime.h>
#include <math.h>

#define BX   1024
#define NA   16
#define NM   16
#define MENU 256
#define KK   257     // MENU + 1 (null option)

typedef float v4f __attribute__((ext_vector_type(4)));

// out layout (flat, return order)
#define OFF_CHOICE  0
#define OFF_ITEM    ((size_t)BX * KK)
#define OFF_UTIL    (OFF_ITEM + (size_t)BX * 256)
#define OFF_PAY     (OFF_UTIL + (size_t)NA * BX)
#define OFF_ALLOCSP (OFF_PAY  + (size_t)NA * BX)
#define OFF_BIDREV  (OFF_ALLOCSP + (size_t)BX * KK * 256)

// ---------------- Kernel A: flat grid-stride copy + fused dot ----------------
// Shaped like the 6.3 TB/s float4 copy: 2048 blocks x 256 threads, grid-stride,
// no LDS, no barriers, ~32 VGPR. Each wave-iteration covers exactly one (b,k)
// 16x16 slab (64 float4). Dot is 4 VALU + 2 shfl; paw (unscaled) goes to ws.
__global__ __launch_bounds__(256) void stream_kernel(
    const float* __restrict__ bids,
    const float* __restrict__ values,
    const float* __restrict__ allocs,
    float* __restrict__ out,
    float* __restrict__ paw_ws)
{
    const size_t nf4    = (size_t)BX * MENU * 64;            // 16,777,216 float4
    const size_t stride = (size_t)gridDim.x * blockDim.x;
    size_t i = (size_t)blockIdx.x * blockDim.x + threadIdx.x;

    const v4f* __restrict__ src = (const v4f*)allocs;
    const v4f* __restrict__ vv  = (const v4f*)values;
    const v4f* __restrict__ bb  = (const v4f*)bids;
    v4f*       __restrict__ dst = (v4f*)(out + OFF_ALLOCSP);

    const int l    = threadIdx.x & 63;     // lane
    const int nloc = l >> 2;               // agent index for this lane group

    #pragma unroll 4
    for (; i < nf4; i += stride) {
        const int b   = (int)(i >> 14);          // 16384 float4 per b
        const int rem = (int)(i & 16383);
        const int k   = rem >> 6;

        v4f a = src[i];
        v4f vb4 = vv[b * 64 + (rem & 63)] - bb[b * 64 + (rem & 63)];   // L2-hot
        dst[(size_t)b * (KK * 64) + rem] = a;    // allocs_p copy (rows 0..255)

        float d = a.x * vb4.x + a.y * vb4.y + a.z * vb4.z + a.w * vb4.w;
        d += __shfl_xor(d, 1);
        d += __shfl_xor(d, 2);                   // sum over this agent's 16 m's
        if ((l & 3) == 0)
            paw_ws[(size_t)b * 4096 + k * 16 + nloc] = d;   // unscaled
    }
}

// ---------------- Kernel B: softmax + counterfactuals + epilogue ----------------
__global__ __launch_bounds__(256) void tail_kernel(
    const float* __restrict__ bids,
    const float* __restrict__ values,
    const float* __restrict__ allocs,
    const float* __restrict__ w,
    const float* __restrict__ bvec,
    const int*   __restrict__ tptr,
    const float* __restrict__ paw_ws,
    float* __restrict__ out)
{
    const int b   = blockIdx.x;
    const int tid = threadIdx.x;

    __shared__ float wl[16];
    __shared__ float paw[KK][17];
    __shared__ float tw_s[KK];
    __shared__ float bp_s[KK];
    __shared__ float ch_s[KK];
    __shared__ float red[8];

    int iv = *tptr;
    float temp = (iv > 0 && iv < (1 << 24)) ? (float)iv : __int_as_float(iv);

    float* out_choice  = out + OFF_CHOICE;
    float* out_item    = out + OFF_ITEM;
    float* out_util    = out + OFF_UTIL;
    float* out_pay     = out + OFF_PAY;
    float* out_allocsp = out + OFF_ALLOCSP;
    float* out_bidrev  = out + OFF_BIDREV;

    // zero null row of allocs_p
    if (tid < 64) {
        v4f z = (v4f){0.f, 0.f, 0.f, 0.f};
        ((v4f*)(out_allocsp + (size_t)b * KK * 256 + (size_t)MENU * 256))[tid] = z;
    }

    // load paw[256][16] from ws (unscaled), scale by w on the fly
    {
        const v4f* pws = (const v4f*)(paw_ws + (size_t)b * 4096);
        const v4f* wv  = (const v4f*)(w + b * 16);
        #pragma unroll
        for (int j = 0; j < 4; ++j) {
            v4f t = pws[tid * 4 + j] * wv[j];    // broadcast L2 load of w
            paw[tid][j * 4 + 0] = t.x;
            paw[tid][j * 4 + 1] = t.y;
            paw[tid][j * 4 + 2] = t.z;
            paw[tid][j * 4 + 3] = t.w;
        }
    }
    bp_s[tid] = bvec[(size_t)b * 256 + tid];
    if (tid < 16) { wl[tid] = w[b * 16 + tid]; paw[MENU][tid] = 0.0f; }
    if (tid == 0) { bp_s[MENU] = 0.0f; tw_s[MENU] = 0.0f; }

    float tw = 0.0f;
    #pragma unroll
    for (int n = 0; n < 16; ++n) tw += paw[tid][n];
    tw_s[tid] = tw;
    const float logit = (tw + bp_s[tid]) * temp;

    const int wid = tid >> 6;
    float mx = logit;
    #pragma unroll
    for (int off = 32; off; off >>= 1) mx = fmaxf(mx, __shfl_xor(mx, off));
    if ((tid & 63) == 0) red[wid] = mx;
    __syncthreads();                                    // S1 (fences paw/tw_s too)
    mx = fmaxf(fmaxf(red[0], red[1]), fmaxf(red[2], red[3]));
    mx = fmaxf(mx, 0.0f);                               // null-option logit = 0

    float e = __expf(logit - mx);
    float s = e;
    #pragma unroll
    for (int off = 32; off; off >>= 1) s += __shfl_xor(s, off);
    if ((tid & 63) == 0) red[4 + wid] = s;
    __syncthreads();                                    // S2
    s = red[4] + red[5] + red[6] + red[7] + __expf(0.0f - mx);
    const float inv = 1.0f / s;

    const float c = e * inv;
    ch_s[tid] = c;
    out_choice[(size_t)b * KK + tid] = c;
    if (tid == 0) {
        float cn = __expf(0.0f - mx) * inv;
        ch_s[MENU] = cn;
        out_choice[(size_t)b * KK + MENU] = cn;
    }

    float qv = c * (tw + bp_s[tid]);
    #pragma unroll
    for (int off = 32; off; off >>= 1) qv += __shfl_xor(qv, off);
    __syncthreads();                                    // S3
    if ((tid & 63) == 0) red[wid] = qv;
    __syncthreads();                                    // S4 (fences ch_s)
    const float cs_ab = red[0] + red[1] + red[2] + red[3];

    const int ai = tid >> 4;
    const int aj = tid & 15;
    float m1 = -1e30f;
    for (int k = aj; k < KK; k += 16) {
        float tr = tw_s[k] - paw[k][ai];
        m1 = fmaxf(m1, (tr + bp_s[k]) * temp);
    }
    #pragma unroll
    for (int off = 8; off; off >>= 1) m1 = fmaxf(m1, __shfl_xor(m1, off));
    float ss = 0.f, srs = 0.f, srb = 0.f;
    for (int k = aj; k < KK; k += 16) {
        float tr = tw_s[k] - paw[k][ai];
        float bp = bp_s[k];
        float eo = __expf((tr + bp) * temp - m1);
        ss  += eo;
        srs += eo * tr;
        srb += eo * bp;
    }
    #pragma unroll
    for (int off = 8; off; off >>= 1) {
        ss  += __shfl_xor(ss, off);
        srs += __shfl_xor(srs, off);
        srb += __shfl_xor(srb, off);
    }
    float paypre = 0.0f;
    if (aj == 0) paypre = (cs_ab - (srs + srb) / ss) / wl[ai];

    float ia = 0.0f;
    const float* ab = allocs + (size_t)b * MENU * 256 + tid;
    for (int k = 0; k < MENU; ++k) {
        float cc = ch_s[k];
        if (cc > 1e-9f) ia += cc * ab[(size_t)k * 256];
    }
    out_item[(size_t)b * 256 + tid] = ia;

    float pb = ia * bids[(size_t)b * 256 + tid];
    float pv = ia * values[(size_t)b * 256 + tid];
    #pragma unroll
    for (int off = 1; off <= 8; off <<= 1) {
        pb += __shfl_xor(pb, off);
        pv += __shfl_xor(pv, off);
    }
    if (aj == 0) {
        float pay = paypre + pb;
        out_bidrev[(size_t)ai * BX + b] = pb;
        out_pay[(size_t)ai * BX + b]    = pay;
        out_util[(size_t)ai * BX + b]   = pv - pay;
    }
}

// ---------------- Fallback: proven single-kernel path ----------------
__global__ __launch_bounds__(256) void auction_kernel(
    const float* __restrict__ bids, const float* __restrict__ values,
    const float* __restrict__ allocs, const float* __restrict__ w,
    const float* __restrict__ bvec, const int* __restrict__ tptr,
    float* __restrict__ out)
{
    const int b   = blockIdx.x;
    const int tid = threadIdx.x;

    __shared__ __align__(16) float vb[256];
    __shared__ float wl[16];
    __shared__ float paw[KK][17];
    __shared__ float tw_s[KK];
    __shared__ float bp_s[KK];
    __shared__ float ch_s[KK];
    __shared__ float red[8];

    int iv = *tptr;
    float temp = (iv > 0 && iv < (1 << 24)) ? (float)iv : __int_as_float(iv);

    float* out_choice  = out + OFF_CHOICE;
    float* out_item    = out + OFF_ITEM;
    float* out_util    = out + OFF_UTIL;
    float* out_pay     = out + OFF_PAY;
    float* out_allocsp = out + OFF_ALLOCSP;
    float* out_bidrev  = out + OFF_BIDREV;

    vb[tid]   = values[(size_t)b * 256 + tid] - bids[(size_t)b * 256 + tid];
    bp_s[tid] = bvec[(size_t)b * 256 + tid];
    if (tid < 16) { wl[tid] = w[b * 16 + tid]; paw[MENU][tid] = 0.0f; }
    if (tid == 0) { bp_s[MENU] = 0.0f; tw_s[MENU] = 0.0f; }
    __syncthreads();

    {
        const v4f* arow = (const v4f*)(allocs + (size_t)b * MENU * 256);
        v4f*       orow = (v4f*)(out_allocsp + (size_t)b * KK * 256);
        const int ksub = tid >> 6;
        const int l    = tid & 63;
        const v4f vb4  = ((const v4f*)vb)[l];
        const float wn = wl[l >> 2];
        #pragma unroll 8
        for (int kb = 0; kb < 64; ++kb) {
            int k = kb * 4 + ksub;
            v4f a = arow[k * 64 + l];
            orow[k * 64 + l] = a;
            float d = a.x * vb4.x + a.y * vb4.y + a.z * vb4.z + a.w * vb4.w;
            d += __shfl_xor(d, 1);
            d += __shfl_xor(d, 2);
            if ((l & 3) == 0) paw[k][l >> 2] = wn * d;
        }
        if (tid < 64) orow[MENU * 64 + tid] = (v4f){0.f, 0.f, 0.f, 0.f};
    }
    __syncthreads();

    float tw = 0.0f;
    #pragma unroll
    for (int n = 0; n < 16; ++n) tw += paw[tid][n];
    tw_s[tid] = tw;
    const float logit = (tw + bp_s[tid]) * temp;

    const int wid = tid >> 6;
    float mx = logit;
    #pragma unroll
    for (int off = 32; off; off >>= 1) mx = fmaxf(mx, __shfl_xor(mx, off));
    if ((tid & 63) == 0) red[wid] = mx;
    __syncthreads();
    mx = fmaxf(fmaxf(red[0], red[1]), fmaxf(red[2], red[3]));
    mx = fmaxf(mx, 0.0f);

    float e = __expf(logit - mx);
    float s = e;
    #pragma unroll
    for (int off = 32; off; off >>= 1) s += __shfl_xor(s, off);
    if ((tid & 63) == 0) red[4 + wid] = s;
    __syncthreads();
    s = red[4] + red[5] + red[6] + red[7] + __expf(0.0f - mx);
    const float inv = 1.0f / s;

    const float c = e * inv;
    ch_s[tid] = c;
    out_choice[(size_t)b * KK + tid] = c;
    if (tid == 0) {
        float cn = __expf(0.0f - mx) * inv;
        ch_s[MENU] = cn;
        out_choice[(size_t)b * KK + MENU] = cn;
    }

    float qv = c * (tw + bp_s[tid]);
    #pragma unroll
    for (int off = 32; off; off >>= 1) qv += __shfl_xor(qv, off);
    __syncthreads();
    if ((tid & 63) == 0) red[wid] = qv;
    __syncthreads();
    const float cs_ab = red[0] + red[1] + red[2] + red[3];

    const int ai = tid >> 4;
    const int aj = tid & 15;
    float m1 = -1e30f;
    for (int k = aj; k < KK; k += 16) {
        float tr = tw_s[k] - paw[k][ai];
        m1 = fmaxf(m1, (tr + bp_s[k]) * temp);
    }
    #pragma unroll
    for (int off = 8; off; off >>= 1) m1 = fmaxf(m1, __shfl_xor(m1, off));
    float ss = 0.f, srs = 0.f, srb = 0.f;
    for (int k = aj; k < KK; k += 16) {
        float tr = tw_s[k] - paw[k][ai];
        float bp = bp_s[k];
        float eo = __expf((tr + bp) * temp - m1);
        ss  += eo;
        srs += eo * tr;
        srb += eo * bp;
    }
    #pragma unroll
    for (int off = 8; off; off >>= 1) {
        ss  += __shfl_xor(ss, off);
        srs += __shfl_xor(srs, off);
        srb += __shfl_xor(srb, off);
    }
    float paypre = 0.0f;
    if (aj == 0) paypre = (cs_ab - (srs + srb) / ss) / wl[ai];

    float ia = 0.0f;
    const float* ab = allocs + (size_t)b * MENU * 256 + tid;
    for (int k = 0; k < MENU; ++k) {
        float cc = ch_s[k];
        if (cc > 1e-9f) ia += cc * ab[(size_t)k * 256];
    }
    out_item[(size_t)b * 256 + tid] = ia;

    float pb = ia * bids[(size_t)b * 256 + tid];
    float pv = ia * values[(size_t)b * 256 + tid];
    #pragma unroll
    for (int off = 1; off <= 8; off <<= 1) {
        pb += __shfl_xor(pb, off);
        pv += __shfl_xor(pv, off);
    }
    if (aj == 0) {
        float pay = paypre + pb;
        out_bidrev[(size_t)ai * BX + b] = pb;
        out_pay[(size_t)ai * BX + b]    = pay;
        out_util[(size_t)ai * BX + b]   = pv - pay;
    }
}

extern "C" void kernel_launch(void* const* d_in, const int* in_sizes, int n_in,
                              void* d_out, int out_size, void* d_ws, size_t ws_size,
                              hipStream_t stream) {
    (void)in_sizes; (void)n_in; (void)out_size;
    const float* bids   = (const float*)d_in[0];
    const float* values = (const float*)d_in[1];
    const float* allocs = (const float*)d_in[2];
    const float* w      = (const float*)d_in[3];
    const float* bvec   = (const float*)d_in[4];
    const int*   tptr   = (const int*)d_in[5];
    float* out = (float*)d_out;

    const size_t paw_bytes = (size_t)BX * 4096 * sizeof(float);  // 16.8 MB
    if (ws_size >= paw_bytes) {
        float* paw_ws = (float*)d_ws;
        stream_kernel<<<2048, 256, 0, stream>>>(bids, values, allocs, out, paw_ws);
        tail_kernel<<<BX, 256, 0, stream>>>(bids, values, allocs, w, bvec, tptr, paw_ws, out);
    } else {
        auction_kernel<<<BX, 256, 0, stream>>>(bids, values, allocs, w, bvec, tptr, out);
    }
}

// Round 6
// 132.896 us; speedup vs baseline: 1.0683x; 1.0683x over previous
//
#include <hip/hip_runtime.h>
#include <math.h>

#define BX   1024
#define NA   16
#define NM   16
#define MENU 256
#define KK   257     // MENU + 1 (null option)

typedef float v4f __attribute__((ext_vector_type(4)));

// out layout (flat, return order)
#define OFF_CHOICE  0
#define OFF_ITEM    ((size_t)BX * KK)
#define OFF_UTIL    (OFF_ITEM + (size_t)BX * 256)
#define OFF_PAY     (OFF_UTIL + (size_t)NA * BX)
#define OFF_ALLOCSP (OFF_PAY  + (size_t)NA * BX)
#define OFF_BIDREV  (OFF_ALLOCSP + (size_t)BX * KK * 256)

// R1 fused kernel (best measured: 133.8 us), with ONE change: both the
// allocs read stream and the allocs_p write stream are non-temporal, so
// neither allocates/retains in L2/L3. Goal: convert the L3-thrash regime
// (268 MB src vs 256 MB L3, churned by 270 MB write-allocate) into the
// clean dual-stream pattern that hits ~6.3 TB/s on this chip.
__global__ __launch_bounds__(256) void auction_kernel_nt(
    const float* __restrict__ bids, const float* __restrict__ values,
    const float* __restrict__ allocs, const float* __restrict__ w,
    const float* __restrict__ bvec, const int* __restrict__ tptr,
    float* __restrict__ out)
{
    const int b   = blockIdx.x;
    const int tid = threadIdx.x;

    __shared__ __align__(16) float vb[256];
    __shared__ float wl[16];
    __shared__ float paw[KK][17];
    __shared__ float tw_s[KK];
    __shared__ float bp_s[KK];
    __shared__ float ch_s[KK];
    __shared__ float red[8];

    int iv = *tptr;
    float temp = (iv > 0 && iv < (1 << 24)) ? (float)iv : __int_as_float(iv);

    float* out_choice  = out + OFF_CHOICE;
    float* out_item    = out + OFF_ITEM;
    float* out_util    = out + OFF_UTIL;
    float* out_pay     = out + OFF_PAY;
    float* out_allocsp = out + OFF_ALLOCSP;
    float* out_bidrev  = out + OFF_BIDREV;

    vb[tid]   = values[(size_t)b * 256 + tid] - bids[(size_t)b * 256 + tid];
    bp_s[tid] = bvec[(size_t)b * 256 + tid];
    if (tid < 16) { wl[tid] = w[b * 16 + tid]; paw[MENU][tid] = 0.0f; }
    if (tid == 0) { bp_s[MENU] = 0.0f; tw_s[MENU] = 0.0f; }
    __syncthreads();

    // ---- pass 1: stream allocs once (NT load) -> paw, copy out (NT store) ----
    {
        const v4f* arow = (const v4f*)(allocs + (size_t)b * MENU * 256);
        v4f*       orow = (v4f*)(out_allocsp + (size_t)b * KK * 256);
        const int ksub = tid >> 6;
        const int l    = tid & 63;
        const v4f vb4  = ((const v4f*)vb)[l];
        const float wn = wl[l >> 2];
        #pragma unroll 8
        for (int kb = 0; kb < 64; ++kb) {
            int k = kb * 4 + ksub;
            v4f a = __builtin_nontemporal_load(arow + k * 64 + l);
            __builtin_nontemporal_store(a, orow + k * 64 + l);
            float d = a.x * vb4.x + a.y * vb4.y + a.z * vb4.z + a.w * vb4.w;
            d += __shfl_xor(d, 1);
            d += __shfl_xor(d, 2);
            if ((l & 3) == 0) paw[k][l >> 2] = wn * d;
        }
        if (tid < 64) {
            v4f z = (v4f){0.f, 0.f, 0.f, 0.f};
            __builtin_nontemporal_store(z, orow + MENU * 64 + tid);
        }
    }
    __syncthreads();

    // ---- main softmax over K=257 ----
    float tw = 0.0f;
    #pragma unroll
    for (int n = 0; n < 16; ++n) tw += paw[tid][n];
    tw_s[tid] = tw;
    const float logit = (tw + bp_s[tid]) * temp;

    const int wid = tid >> 6;
    float mx = logit;
    #pragma unroll
    for (int off = 32; off; off >>= 1) mx = fmaxf(mx, __shfl_xor(mx, off));
    if ((tid & 63) == 0) red[wid] = mx;
    __syncthreads();
    mx = fmaxf(fmaxf(red[0], red[1]), fmaxf(red[2], red[3]));
    mx = fmaxf(mx, 0.0f);                               // null-option logit = 0

    float e = __expf(logit - mx);
    float s = e;
    #pragma unroll
    for (int off = 32; off; off >>= 1) s += __shfl_xor(s, off);
    if ((tid & 63) == 0) red[4 + wid] = s;
    __syncthreads();
    s = red[4] + red[5] + red[6] + red[7] + __expf(0.0f - mx);
    const float inv = 1.0f / s;

    const float c = e * inv;
    ch_s[tid] = c;
    out_choice[(size_t)b * KK + tid] = c;
    if (tid == 0) {
        float cn = __expf(0.0f - mx) * inv;
        ch_s[MENU] = cn;
        out_choice[(size_t)b * KK + MENU] = cn;
    }

    // chosen_sum + alloc_b
    float qv = c * (tw + bp_s[tid]);
    #pragma unroll
    for (int off = 32; off; off >>= 1) qv += __shfl_xor(qv, off);
    __syncthreads();
    if ((tid & 63) == 0) red[wid] = qv;
    __syncthreads();
    const float cs_ab = red[0] + red[1] + red[2] + red[3];

    // ---- 16 counterfactual softmaxes ----
    const int ai = tid >> 4;
    const int aj = tid & 15;
    float m1 = -1e30f;
    for (int k = aj; k < KK; k += 16) {
        float tr = tw_s[k] - paw[k][ai];
        m1 = fmaxf(m1, (tr + bp_s[k]) * temp);
    }
    #pragma unroll
    for (int off = 8; off; off >>= 1) m1 = fmaxf(m1, __shfl_xor(m1, off));
    float ss = 0.f, srs = 0.f, srb = 0.f;
    for (int k = aj; k < KK; k += 16) {
        float tr = tw_s[k] - paw[k][ai];
        float bp = bp_s[k];
        float eo = __expf((tr + bp) * temp - m1);
        ss  += eo;
        srs += eo * tr;
        srb += eo * bp;
    }
    #pragma unroll
    for (int off = 8; off; off >>= 1) {
        ss  += __shfl_xor(ss, off);
        srs += __shfl_xor(srs, off);
        srb += __shfl_xor(srb, off);
    }
    float paypre = 0.0f;
    if (aj == 0) paypre = (cs_ab - (srs + srb) / ss) / wl[ai];

    // ---- pass 2: sparse item_allocation + epilogue (normal loads) ----
    float ia = 0.0f;
    const float* ab = allocs + (size_t)b * MENU * 256 + tid;
    for (int k = 0; k < MENU; ++k) {
        float cc = ch_s[k];
        if (cc > 1e-9f) ia += cc * ab[(size_t)k * 256];
    }
    out_item[(size_t)b * 256 + tid] = ia;

    float pb = ia * bids[(size_t)b * 256 + tid];
    float pv = ia * values[(size_t)b * 256 + tid];
    #pragma unroll
    for (int off = 1; off <= 8; off <<= 1) {
        pb += __shfl_xor(pb, off);
        pv += __shfl_xor(pv, off);
    }
    if (aj == 0) {
        float pay = paypre + pb;
        out_bidrev[(size_t)ai * BX + b] = pb;
        out_pay[(size_t)ai * BX + b]    = pay;
        out_util[(size_t)ai * BX + b]   = pv - pay;
    }
}

extern "C" void kernel_launch(void* const* d_in, const int* in_sizes, int n_in,
                              void* d_out, int out_size, void* d_ws, size_t ws_size,
                              hipStream_t stream) {
    (void)in_sizes; (void)n_in; (void)d_ws; (void)ws_size; (void)out_size;
    const float* bids   = (const float*)d_in[0];
    const float* values = (const float*)d_in[1];
    const float* allocs = (const float*)d_in[2];
    const float* w      = (const float*)d_in[3];
    const float* bvec   = (const float*)d_in[4];
    const int*   tptr   = (const int*)d_in[5];
    float* out = (float*)d_out;

    auction_kernel_nt<<<BX, 256, 0, stream>>>(bids, values, allocs, w, bvec, tptr, out);
}